// Round 4
// baseline (1891.297 us; speedup 1.0000x reference)
//
#include <hip/hip_runtime.h>

#define Tn   2048
#define Dn   1024
#define KDn  256
#define NHn  16
#define NKVn 4
#define Rn   4096   // B*T

typedef short bf16x8 __attribute__((ext_vector_type(8)));
typedef float f32x4  __attribute__((ext_vector_type(4)));

// ---- device-global intermediates; referenced ONLY from device code ---------
__device__ unsigned short g_q[(size_t)Rn * Dn];   // 8 MB
__device__ unsigned short g_k[(size_t)Rn * KDn];  // 2 MB
__device__ unsigned short g_v[(size_t)Rn * KDn];  // 2 MB
__device__ unsigned short g_y[(size_t)Rn * Dn];   // 8 MB
__device__ float g_tq[Rn * 8];
__device__ float g_tv[Rn * 8];

static __device__ __forceinline__ float bf2f(unsigned short u) {
    return __uint_as_float(((unsigned)u) << 16);
}
static __device__ __forceinline__ unsigned short f2bf(float f) {
    unsigned u = __float_as_uint(f);
    u += 0x7fffu + ((u >> 16) & 1u);   // round-to-nearest-even
    return (unsigned short)(u >> 16);
}
static __device__ __forceinline__ float wave_sum(float s) {
    #pragma unroll
    for (int off = 32; off; off >>= 1) s += __shfl_xor(s, off);
    return s;
}
// load 8 fp32, round to bf16, store 16B into LDS
static __device__ __forceinline__ void stage8(unsigned short* dst, const float* src) {
    float4 a = *(const float4*)src;
    float4 b = *(const float4*)(src + 4);
    unsigned short t8[8] = {f2bf(a.x), f2bf(a.y), f2bf(a.z), f2bf(a.w),
                            f2bf(b.x), f2bf(b.y), f2bf(b.z), f2bf(b.w)};
    *(uint4*)dst = *(const uint4*)t8;
}

// ---------------- LoRA temporaries: tq = x@Aq^T, tv = x@Av^T ----------------
__global__ __launch_bounds__(256)
void lora_tmp(const float* __restrict__ x,
              const float* __restrict__ Aq,
              const float* __restrict__ Av) {
    int tid = threadIdx.x, wave = tid >> 6, lane = tid & 63;
    int row = blockIdx.x * 4 + wave;
    const float* xr = x + (size_t)row * Dn;
    float aq[8], av[8];
    #pragma unroll
    for (int r = 0; r < 8; r++) { aq[r] = 0.f; av[r] = 0.f; }
    for (int it = 0; it < Dn / 64; it++) {
        int j = lane + it * 64;
        float xv = xr[j];
        #pragma unroll
        for (int r = 0; r < 8; r++) aq[r] += xv * Aq[r * Dn + j];
        #pragma unroll
        for (int r = 0; r < 8; r++) av[r] += xv * Av[r * Dn + j];
    }
    #pragma unroll
    for (int r = 0; r < 8; r++) { aq[r] = wave_sum(aq[r]); av[r] = wave_sum(av[r]); }
    if (lane == 0) {
        #pragma unroll
        for (int r = 0; r < 8; r++) { g_tq[row * 8 + r] = aq[r]; g_tv[row * 8 + r] = av[r]; }
    }
}

// ---- MFMA GEMM: C = A(MxK) @ W(NxK)^T (+ t(Mx8) @ Bl(Nx8)^T) ---------------
// Inputs fp32 (converted to bf16 at staging). DST: 0=g_q,1=g_k,2=g_v (bf16),
// 3=Cout (fp32). ASEL: 0=Afp (fp32), 1=g_y (bf16). TSEL: 0=g_tq, 1=g_tv.
template<int LORA, int DST, int ASEL, int TSEL>
__global__ __launch_bounds__(256, 2)
void gemm_bt(const float* __restrict__ Afp,
             const float* __restrict__ W,
             float* __restrict__ Cout,
             const float* __restrict__ Bl,
             int M, int N, int K) {
    const float* tl = (TSEL == 0) ? g_tq : g_tv;

    __shared__ __align__(16) unsigned short As[64 * 40];
    __shared__ __align__(16) unsigned short Ws[64 * 40];
    int tid = threadIdx.x;
    int w = tid >> 6, lane = tid & 63;
    int m_ = lane & 15, quad = lane >> 4;
    int n0 = blockIdx.x * 64, m0 = blockIdx.y * 64;
    int srow = tid >> 2, sseg = (tid & 3) * 8;

    f32x4 acc[4];
    #pragma unroll
    for (int i = 0; i < 4; i++) acc[i] = (f32x4){0.f, 0.f, 0.f, 0.f};

    for (int k0 = 0; k0 < K; k0 += 32) {
        __syncthreads();
        if (ASEL == 0) {
            stage8(&As[srow * 40 + sseg], Afp + (size_t)(m0 + srow) * K + k0 + sseg);
        } else {
            *(uint4*)&As[srow * 40 + sseg] =
                *(const uint4*)(g_y + (size_t)(m0 + srow) * K + k0 + sseg);
        }
        stage8(&Ws[srow * 40 + sseg], W + (size_t)(n0 + srow) * K + k0 + sseg);
        __syncthreads();
        bf16x8 af = *(const bf16x8*)&As[(w * 16 + m_) * 40 + quad * 8];
        #pragma unroll
        for (int i = 0; i < 4; i++) {
            bf16x8 bfv = *(const bf16x8*)&Ws[(i * 16 + m_) * 40 + quad * 8];
            acc[i] = __builtin_amdgcn_mfma_f32_16x16x32_bf16(af, bfv, acc[i], 0, 0, 0);
        }
    }

    float tvr[4][8], blc[4][8];
    if (LORA) {
        #pragma unroll
        for (int r = 0; r < 4; r++) {
            int row = m0 + w * 16 + quad * 4 + r;
            const float* tp = tl + (size_t)row * 8;
            #pragma unroll
            for (int j = 0; j < 8; j++) tvr[r][j] = tp[j];
        }
        #pragma unroll
        for (int i = 0; i < 4; i++) {
            int col = n0 + i * 16 + m_;
            const float* bp = Bl + (size_t)col * 8;
            #pragma unroll
            for (int j = 0; j < 8; j++) blc[i][j] = bp[j];
        }
    }
    #pragma unroll
    for (int i = 0; i < 4; i++) {
        int col = n0 + i * 16 + m_;
        #pragma unroll
        for (int r = 0; r < 4; r++) {
            int row = m0 + w * 16 + quad * 4 + r;
            float val = acc[i][r];
            if (LORA) {
                #pragma unroll
                for (int j = 0; j < 8; j++) val += tvr[r][j] * blc[i][j];
            }
            if (DST == 3) {
                Cout[(size_t)row * N + col] = val;
            } else {
                unsigned short* C = (DST == 0) ? g_q : (DST == 1) ? g_k : g_v;
                C[(size_t)row * N + col] = f2bf(val);
            }
        }
    }
}

// -------- RMSNorm + partial RoPE (+gain for q), in place on g_q / g_k -------
__global__ __launch_bounds__(256)
void nrg_kernel(const float* __restrict__ gain) {
    int tid = threadIdx.x;
    int u = blockIdx.y * 4 + (tid >> 6);   // 0..15: q heads, 16..19: k heads
    int lane = tid & 63;
    int row = blockIdx.x;
    int t = row & (Tn - 1);

    unsigned short* buf;
    size_t off;
    if (u < 16) { buf = g_q; off = (size_t)row * Dn + u * 64 + lane; }
    else        { buf = g_k; off = (size_t)row * KDn + (u - 16) * 64 + lane; }

    float v = bf2f(buf[off]);
    float s = wave_sum(v * v);
    float xv = v * rsqrtf(s * (1.0f / 64.0f) + 1.1920929e-7f);
    float p = __shfl_xor(xv, 8);
    if (lane < 16) {
        int j = lane & 7;
        float fr = (float)t * exp2f(-(float)j * 1.6609640474436813f); // base^(-j/8)
        float c = cosf(fr), sn = sinf(fr);
        xv = (lane < 8) ? (xv * c + p * sn) : (p * sn - xv * c);
    }
    if (u < 16) xv *= gain[u];
    buf[off] = f2bf(xv);
}

// ---------------- flash attention, lane = q row, 32-key LDS tiles -----------
__global__ __launch_bounds__(256, 1)
void attn_kernel() {
    __shared__ __align__(16) float ks[32][64];
    __shared__ __align__(16) float vs[32][64];
    int tid = threadIdx.x;
    int wave = tid >> 6, lane = tid & 63;
    int b = blockIdx.z, h = blockIdx.y, kvh = h >> 2;
    int qt = blockIdx.x * 256 + wave * 64 + lane;

    const unsigned short* qp = g_q + ((size_t)(b * Tn + qt)) * Dn + h * 64;
    float q[64];
    const float qs = 0.125f * 1.44269504088896f;  // 1/sqrt(HD) * log2(e)
    #pragma unroll
    for (int i = 0; i < 8; i++) {
        uint4 uv = ((const uint4*)qp)[i];
        unsigned uu[4] = {uv.x, uv.y, uv.z, uv.w};
        #pragma unroll
        for (int p2 = 0; p2 < 4; p2++) {
            q[i * 8 + p2 * 2 + 0] = __uint_as_float(uu[p2] << 16) * qs;
            q[i * 8 + p2 * 2 + 1] = __uint_as_float(uu[p2] & 0xffff0000u) * qs;
        }
    }
    float O[64];
    #pragma unroll
    for (int d = 0; d < 64; d++) O[d] = 0.f;
    float m = -1e30f, l = 0.f;

    int ntiles = (blockIdx.x * 256 + 256) >> 5;
    int wave_max = blockIdx.x * 256 + wave * 64 + 63;
    const unsigned* kp = (const unsigned*)g_k;
    const unsigned* vp = (const unsigned*)g_v;

    for (int kt0 = 0; kt0 < ntiles; kt0++) {
        __syncthreads();
        #pragma unroll
        for (int s4 = 0; s4 < 4; s4++) {
            int idx = tid + s4 * 256;
            int j = idx >> 5, dd = idx & 31;
            int kt = kt0 * 32 + j;
            size_t off = ((size_t)(b * Tn + kt) * NKVn + kvh) * 32 + dd;
            unsigned kw = kp[off], vw = vp[off];
            ks[j][2 * dd]     = __uint_as_float(kw << 16);
            ks[j][2 * dd + 1] = __uint_as_float(kw & 0xffff0000u);
            vs[j][2 * dd]     = __uint_as_float(vw << 16);
            vs[j][2 * dd + 1] = __uint_as_float(vw & 0xffff0000u);
        }
        __syncthreads();
        if (kt0 * 32 > wave_max) continue;   // wave-uniform; barriers stay aligned

        float sc[32];
        #pragma unroll
        for (int j = 0; j < 32; j++) {
            const float4* kr = (const float4*)ks[j];
            float a0 = 0.f, a1 = 0.f, a2 = 0.f, a3 = 0.f;
            #pragma unroll
            for (int d4 = 0; d4 < 16; d4++) {
                float4 kv4 = kr[d4];
                a0 += q[d4 * 4 + 0] * kv4.x;
                a1 += q[d4 * 4 + 1] * kv4.y;
                a2 += q[d4 * 4 + 2] * kv4.z;
                a3 += q[d4 * 4 + 3] * kv4.w;
            }
            float s = (a0 + a1) + (a2 + a3);
            int kpos = kt0 * 32 + j;
            sc[j] = (kpos <= qt) ? s : -1e30f;
        }
        float tm = sc[0];
        #pragma unroll
        for (int j = 1; j < 32; j++) tm = fmaxf(tm, sc[j]);
        float mn = fmaxf(m, tm);
        float alpha = exp2f(m - mn);
        l *= alpha;
        #pragma unroll
        for (int d = 0; d < 64; d++) O[d] *= alpha;
        float ps = 0.f;
        #pragma unroll
        for (int j = 0; j < 32; j++) { sc[j] = exp2f(sc[j] - mn); ps += sc[j]; }
        l += ps;
        m = mn;
        #pragma unroll
        for (int j = 0; j < 32; j++) {
            float pj = sc[j];
            const float4* vr = (const float4*)vs[j];
            #pragma unroll
            for (int d4 = 0; d4 < 16; d4++) {
                float4 vv = vr[d4];
                O[d4 * 4 + 0] += pj * vv.x;
                O[d4 * 4 + 1] += pj * vv.y;
                O[d4 * 4 + 2] += pj * vv.z;
                O[d4 * 4 + 3] += pj * vv.w;
            }
        }
    }
    float inv_l = 1.0f / l;
    unsigned short* yp = g_y + ((size_t)(b * Tn + qt)) * Dn + h * 64;
    #pragma unroll
    for (int d = 0; d < 64; d++) yp[d] = f2bf(O[d] * inv_l);
}

// ----------------------------------------------------------------------------
extern "C" void kernel_launch(void* const* d_in, const int* in_sizes, int n_in,
                              void* d_out, int out_size, void* d_ws, size_t ws_size,
                              hipStream_t stream) {
    const float* x  = (const float*)d_in[0];
    const float* Wq = (const float*)d_in[1];
    const float* Wk = (const float*)d_in[2];
    const float* Wv = (const float*)d_in[3];
    const float* Wp = (const float*)d_in[4];
    const float* qg = (const float*)d_in[5];
    const float* Aq = (const float*)d_in[6];
    const float* Bq = (const float*)d_in[7];
    const float* Av = (const float*)d_in[8];
    const float* Bv = (const float*)d_in[9];
    float* out = (float*)d_out;

    lora_tmp<<<dim3(Rn / 4), dim3(256), 0, stream>>>(x, Aq, Av);
    gemm_bt<1, 0, 0, 0><<<dim3(Dn / 64, Rn / 64), dim3(256), 0, stream>>>(
        x, Wq, nullptr, Bq, Rn, Dn, Dn);
    gemm_bt<0, 1, 0, 0><<<dim3(KDn / 64, Rn / 64), dim3(256), 0, stream>>>(
        x, Wk, nullptr, nullptr, Rn, KDn, Dn);
    gemm_bt<1, 2, 0, 1><<<dim3(KDn / 64, Rn / 64), dim3(256), 0, stream>>>(
        x, Wv, nullptr, Bv, Rn, KDn, Dn);
    nrg_kernel<<<dim3(Rn, 5), dim3(256), 0, stream>>>(qg);
    attn_kernel<<<dim3(Tn / 256, NHn, 2), dim3(256), 0, stream>>>();
    gemm_bt<0, 3, 1, 0><<<dim3(Dn / 64, Rn / 64), dim3(256), 0, stream>>>(
        nullptr, Wp, out, nullptr, Rn, Dn, Dn);
}

// Round 5
// 436.310 us; speedup vs baseline: 4.3348x; 4.3348x over previous
//
#include <hip/hip_runtime.h>

#define Tn   2048
#define Dn   1024
#define KDn  256
#define NHn  16
#define NKVn 4
#define Rn   4096   // B*T

typedef short bf16x8 __attribute__((ext_vector_type(8)));
typedef float f32x4  __attribute__((ext_vector_type(4)));

// ---- device-global intermediates; referenced ONLY from device code ---------
__device__ unsigned short g_q[(size_t)Rn * Dn];              // 8 MB [b][t][h][d]
__device__ unsigned short g_k[(size_t)Rn * KDn];             // 2 MB [b][t][kvh][d]
__device__ unsigned short g_vt[(size_t)2 * NKVn * 64 * Tn];  // 2 MB [b][kvh][d][t]
__device__ unsigned short g_y[(size_t)Rn * Dn];              // 8 MB [b][t][h][d]
__device__ float g_tq[Rn * 8];
__device__ float g_tv[Rn * 8];

static __device__ __forceinline__ float bf2f(unsigned short u) {
    return __uint_as_float(((unsigned)u) << 16);
}
static __device__ __forceinline__ unsigned short f2bf(float f) {
    unsigned u = __float_as_uint(f);
    u += 0x7fffu + ((u >> 16) & 1u);   // round-to-nearest-even
    return (unsigned short)(u >> 16);
}
static __device__ __forceinline__ unsigned pk2bf(float a, float b) {
    return (unsigned)f2bf(a) | ((unsigned)f2bf(b) << 16);
}
static __device__ __forceinline__ float wave_sum(float s) {
    #pragma unroll
    for (int off = 32; off; off >>= 1) s += __shfl_xor(s, off);
    return s;
}
// load 8 fp32, round to bf16, store 16B into LDS
static __device__ __forceinline__ void stage8(unsigned short* dst, const float* src) {
    float4 a = *(const float4*)src;
    float4 b = *(const float4*)(src + 4);
    unsigned short t8[8] = {f2bf(a.x), f2bf(a.y), f2bf(a.z), f2bf(a.w),
                            f2bf(b.x), f2bf(b.y), f2bf(b.z), f2bf(b.w)};
    *(uint4*)dst = *(const uint4*)t8;
}

// ---------------- LoRA temporaries: tq = x@Aq^T, tv = x@Av^T ----------------
__global__ __launch_bounds__(256)
void lora_tmp(const float* __restrict__ x,
              const float* __restrict__ Aq,
              const float* __restrict__ Av) {
    int tid = threadIdx.x, wave = tid >> 6, lane = tid & 63;
    int row = blockIdx.x * 4 + wave;
    const float* xr = x + (size_t)row * Dn;
    float aq[8], av[8];
    #pragma unroll
    for (int r = 0; r < 8; r++) { aq[r] = 0.f; av[r] = 0.f; }
    for (int it = 0; it < Dn / 64; it++) {
        int j = lane + it * 64;
        float xv = xr[j];
        #pragma unroll
        for (int r = 0; r < 8; r++) aq[r] += xv * Aq[r * Dn + j];
        #pragma unroll
        for (int r = 0; r < 8; r++) av[r] += xv * Av[r * Dn + j];
    }
    #pragma unroll
    for (int r = 0; r < 8; r++) { aq[r] = wave_sum(aq[r]); av[r] = wave_sum(av[r]); }
    if (lane == 0) {
        #pragma unroll
        for (int r = 0; r < 8; r++) { g_tq[row * 8 + r] = aq[r]; g_tv[row * 8 + r] = av[r]; }
    }
}

// ---- MFMA GEMM: C = A(MxK) @ W(NxK)^T (+ t(Mx8) @ Bl(Nx8)^T) ---------------
// DST: 0=g_q, 1=g_k, 2=g_vt (transposed [b][kvh][d][t]), 3=Cout fp32.
// ASEL: 0=Afp (fp32), 1=g_y (bf16). TSEL: 0=g_tq, 1=g_tv.
template<int LORA, int DST, int ASEL, int TSEL>
__global__ __launch_bounds__(256, 2)
void gemm_bt(const float* __restrict__ Afp,
             const float* __restrict__ W,
             float* __restrict__ Cout,
             const float* __restrict__ Bl,
             int M, int N, int K) {
    const float* tl = (TSEL == 0) ? g_tq : g_tv;

    __shared__ __align__(16) unsigned short As[64 * 40];
    __shared__ __align__(16) unsigned short Ws[64 * 40];
    int tid = threadIdx.x;
    int w = tid >> 6, lane = tid & 63;
    int m_ = lane & 15, quad = lane >> 4;
    int n0 = blockIdx.x * 64, m0 = blockIdx.y * 64;
    int srow = tid >> 2, sseg = (tid & 3) * 8;

    f32x4 acc[4];
    #pragma unroll
    for (int i = 0; i < 4; i++) acc[i] = (f32x4){0.f, 0.f, 0.f, 0.f};

    for (int k0 = 0; k0 < K; k0 += 32) {
        __syncthreads();
        if (ASEL == 0) {
            stage8(&As[srow * 40 + sseg], Afp + (size_t)(m0 + srow) * K + k0 + sseg);
        } else {
            *(uint4*)&As[srow * 40 + sseg] =
                *(const uint4*)(g_y + (size_t)(m0 + srow) * K + k0 + sseg);
        }
        stage8(&Ws[srow * 40 + sseg], W + (size_t)(n0 + srow) * K + k0 + sseg);
        __syncthreads();
        bf16x8 af = *(const bf16x8*)&As[(w * 16 + m_) * 40 + quad * 8];
        #pragma unroll
        for (int i = 0; i < 4; i++) {
            bf16x8 bfv = *(const bf16x8*)&Ws[(i * 16 + m_) * 40 + quad * 8];
            acc[i] = __builtin_amdgcn_mfma_f32_16x16x32_bf16(af, bfv, acc[i], 0, 0, 0);
        }
    }

    float tvr[4][8], blc[4][8];
    if (LORA) {
        #pragma unroll
        for (int r = 0; r < 4; r++) {
            int row = m0 + w * 16 + quad * 4 + r;
            const float* tp = tl + (size_t)row * 8;
            #pragma unroll
            for (int j = 0; j < 8; j++) tvr[r][j] = tp[j];
        }
        #pragma unroll
        for (int i = 0; i < 4; i++) {
            int col = n0 + i * 16 + m_;
            const float* bp = Bl + (size_t)col * 8;
            #pragma unroll
            for (int j = 0; j < 8; j++) blc[i][j] = bp[j];
        }
    }
    #pragma unroll
    for (int i = 0; i < 4; i++) {
        int col = n0 + i * 16 + m_;
        #pragma unroll
        for (int r = 0; r < 4; r++) {
            int row = m0 + w * 16 + quad * 4 + r;
            float val = acc[i][r];
            if (LORA) {
                #pragma unroll
                for (int j = 0; j < 8; j++) val += tvr[r][j] * blc[i][j];
            }
            if (DST == 3) {
                Cout[(size_t)row * N + col] = val;
            } else if (DST == 2) {
                // transposed V store: row=(b,t), col=(kvh,d) -> [b][kvh][d][t]
                int b = row >> 11, t = row & (Tn - 1);
                int kvh = col >> 6, d = col & 63;
                g_vt[(((size_t)(b * NKVn + kvh) * 64) + d) * Tn + t] = f2bf(val);
            } else {
                unsigned short* C = (DST == 0) ? g_q : g_k;
                C[(size_t)row * N + col] = f2bf(val);
            }
        }
    }
}

// -------- RMSNorm + partial RoPE (+gain for q), in place on g_q / g_k -------
__global__ __launch_bounds__(256)
void nrg_kernel(const float* __restrict__ gain) {
    int tid = threadIdx.x;
    int u = blockIdx.y * 4 + (tid >> 6);   // 0..15: q heads, 16..19: k heads
    int lane = tid & 63;
    int row = blockIdx.x;
    int t = row & (Tn - 1);

    unsigned short* buf;
    size_t off;
    if (u < 16) { buf = g_q; off = (size_t)row * Dn + u * 64 + lane; }
    else        { buf = g_k; off = (size_t)row * KDn + (u - 16) * 64 + lane; }

    float v = bf2f(buf[off]);
    float s = wave_sum(v * v);
    float xv = v * rsqrtf(s * (1.0f / 64.0f) + 1.1920929e-7f);
    float p = __shfl_xor(xv, 8);
    if (lane < 16) {
        int j = lane & 7;
        float fr = (float)t * exp2f(-(float)j * 1.6609640474436813f); // base^(-j/8)
        float c = cosf(fr), sn = sinf(fr);
        xv = (lane < 8) ? (xv * c + p * sn) : (p * sn - xv * c);
    }
    if (u < 16) xv *= gain[u];
    buf[off] = f2bf(xv);
}

// -------- MFMA flash attention: wave = 16 q rows, 32-key tiles, no barriers --
// S^T = K_tile(16k x 64d) . Q^T  (A=K natural rows, B=Q natural rows)
// O^T = V^T(d x keys) . P^T      (A=g_vt natural rows, B=P^T via wave-private LDS)
__global__ __launch_bounds__(256)
void attn_kernel() {
    __shared__ __align__(16) unsigned short Pt[4][16 * 40];  // per-wave P^T, pad 40
    const float qsc = 0.125f * 1.44269504088896f;  // 1/sqrt(64) * log2(e)
    int tid = threadIdx.x;
    int w = tid >> 6, lane = tid & 63;
    int q_ = lane & 15, quad = lane >> 4;
    int b = blockIdx.z, h = blockIdx.y, kvh = h >> 2;
    int qb = blockIdx.x * 64 + w * 16;
    int qg = qb + q_;

    // Q B-frags: B[k=d=c*32+quad*8+j][n=q_]
    const unsigned short* qrow =
        g_q + ((size_t)(b * Tn + qb + q_) * NHn + h) * 64 + quad * 8;
    bf16x8 Qf0 = *(const bf16x8*)qrow;
    bf16x8 Qf1 = *(const bf16x8*)(qrow + 32);

    // K A-frag base: A[m=key(lane&15)][k=d(quad*8+j)], +hh*16 keys, +c*32 d
    const unsigned short* kbase =
        g_k + ((size_t)(b * Tn + q_) * NKVn + kvh) * 64 + quad * 8;
    // V^T A-frag base: A[m=d chunk (lane&15)][k=key(quad*8+j)], row d -> +c*16 rows
    const unsigned short* vbase =
        g_vt + ((size_t)(b * NKVn + kvh) * 64 + q_) * Tn + quad * 8;

    f32x4 accO[4];
    #pragma unroll
    for (int i = 0; i < 4; i++) accO[i] = (f32x4){0.f, 0.f, 0.f, 0.f};
    float mrun = -1e30f, lrun = 0.f;
    unsigned short* pb = &Pt[w][0];
    int ntiles = (qb + 47) >> 5;   // ceil((qb+16)/32)

    for (int kt = 0; kt < ntiles; kt++) {
        const unsigned short* kp = kbase + (size_t)kt * (32 * NKVn * 64);
        bf16x8 k00 = *(const bf16x8*)(kp);
        bf16x8 k01 = *(const bf16x8*)(kp + 32);
        bf16x8 k10 = *(const bf16x8*)(kp + 16 * NKVn * 64);
        bf16x8 k11 = *(const bf16x8*)(kp + 16 * NKVn * 64 + 32);
        f32x4 s0 = (f32x4){0.f, 0.f, 0.f, 0.f};
        f32x4 s1 = (f32x4){0.f, 0.f, 0.f, 0.f};
        s0 = __builtin_amdgcn_mfma_f32_16x16x32_bf16(k00, Qf0, s0, 0, 0, 0);
        s0 = __builtin_amdgcn_mfma_f32_16x16x32_bf16(k01, Qf1, s0, 0, 0, 0);
        s1 = __builtin_amdgcn_mfma_f32_16x16x32_bf16(k10, Qf0, s1, 0, 0, 0);
        s1 = __builtin_amdgcn_mfma_f32_16x16x32_bf16(k11, Qf1, s1, 0, 0, 0);

        if (kt == ntiles - 1) {   // only the last tile can cross the diagonal
            int k0 = kt * 32 + quad * 4;
            #pragma unroll
            for (int r = 0; r < 4; r++) {
                if (k0 + r > qg)      s0[r] = -1e30f;
                if (k0 + 16 + r > qg) s1[r] = -1e30f;
            }
        }
        float tmax = fmaxf(fmaxf(fmaxf(s0[0], s0[1]), fmaxf(s0[2], s0[3])),
                           fmaxf(fmaxf(s1[0], s1[1]), fmaxf(s1[2], s1[3])));
        tmax = fmaxf(tmax, __shfl_xor(tmax, 16));
        tmax = fmaxf(tmax, __shfl_xor(tmax, 32));
        float mn = fmaxf(mrun, tmax);
        float alpha = exp2f((mrun - mn) * qsc);
        float p0[4], p1[4], ps = 0.f;
        #pragma unroll
        for (int r = 0; r < 4; r++) { p0[r] = exp2f((s0[r] - mn) * qsc); ps += p0[r]; }
        #pragma unroll
        for (int r = 0; r < 4; r++) { p1[r] = exp2f((s1[r] - mn) * qsc); ps += p1[r]; }
        ps += __shfl_xor(ps, 16);
        ps += __shfl_xor(ps, 32);
        lrun = lrun * alpha + ps;
        mrun = mn;
        #pragma unroll
        for (int i = 0; i < 4; i++)
            #pragma unroll
            for (int r = 0; r < 4; r++) accO[i][r] *= alpha;

        // P^T to wave-private LDS (keys quad*4.. and 16+quad*4..), read B-frag
        uint2 w0 = make_uint2(pk2bf(p0[0], p0[1]), pk2bf(p0[2], p0[3]));
        uint2 w1 = make_uint2(pk2bf(p1[0], p1[1]), pk2bf(p1[2], p1[3]));
        *(uint2*)&pb[q_ * 40 + quad * 4] = w0;
        *(uint2*)&pb[q_ * 40 + 16 + quad * 4] = w1;
        bf16x8 pf = *(const bf16x8*)&pb[q_ * 40 + quad * 8];

        const unsigned short* vp = vbase + kt * 32;
        #pragma unroll
        for (int c = 0; c < 4; c++) {
            bf16x8 vf = *(const bf16x8*)(vp + (size_t)c * 16 * Tn);
            accO[c] = __builtin_amdgcn_mfma_f32_16x16x32_bf16(vf, pf, accO[c], 0, 0, 0);
        }
    }

    float invl = 1.0f / lrun;
    unsigned short* yp = g_y + ((size_t)(b * Tn + qb + q_) * NHn + h) * 64;
    #pragma unroll
    for (int c = 0; c < 4; c++) {
        uint2 o = make_uint2(pk2bf(accO[c][0] * invl, accO[c][1] * invl),
                             pk2bf(accO[c][2] * invl, accO[c][3] * invl));
        *(uint2*)&yp[c * 16 + quad * 4] = o;
    }
}

// ----------------------------------------------------------------------------
extern "C" void kernel_launch(void* const* d_in, const int* in_sizes, int n_in,
                              void* d_out, int out_size, void* d_ws, size_t ws_size,
                              hipStream_t stream) {
    const float* x  = (const float*)d_in[0];
    const float* Wq = (const float*)d_in[1];
    const float* Wk = (const float*)d_in[2];
    const float* Wv = (const float*)d_in[3];
    const float* Wp = (const float*)d_in[4];
    const float* qg = (const float*)d_in[5];
    const float* Aq = (const float*)d_in[6];
    const float* Bq = (const float*)d_in[7];
    const float* Av = (const float*)d_in[8];
    const float* Bv = (const float*)d_in[9];
    float* out = (float*)d_out;

    lora_tmp<<<dim3(Rn / 4), dim3(256), 0, stream>>>(x, Aq, Av);
    gemm_bt<1, 0, 0, 0><<<dim3(Dn / 64, Rn / 64), dim3(256), 0, stream>>>(
        x, Wq, nullptr, Bq, Rn, Dn, Dn);
    gemm_bt<0, 1, 0, 0><<<dim3(KDn / 64, Rn / 64), dim3(256), 0, stream>>>(
        x, Wk, nullptr, nullptr, Rn, KDn, Dn);
    gemm_bt<1, 2, 0, 1><<<dim3(KDn / 64, Rn / 64), dim3(256), 0, stream>>>(
        x, Wv, nullptr, Bv, Rn, KDn, Dn);
    nrg_kernel<<<dim3(Rn, 5), dim3(256), 0, stream>>>(qg);
    attn_kernel<<<dim3(Tn / 64, NHn, 2), dim3(256), 0, stream>>>();
    gemm_bt<0, 3, 1, 0><<<dim3(Dn / 64, Rn / 64), dim3(256), 0, stream>>>(
        nullptr, Wp, out, nullptr, Rn, Dn, Dn);
}